// Round 2
// baseline (403.325 us; speedup 1.0000x reference)
//
#include <hip/hip_runtime.h>

// KAN B-spline layer: out[b,o] = sum_i sum_c basis(x[b,i])[c] * cp[i,c,o]
// x: (65536, 64) f32, cp: (64, 12, 64) f32, out: (65536, 64) f32
//
// Dense VALU version. Lane = row; cp accesses are wave-uniform so the
// compiler can scalarize them (SGPR operand of v_fmac). Basis via de Boor
// recursion on the 4-wide support, expanded to the dense 12-vector by selects
// (static register indexing only). Outputs split across 2 waves (32 each)
// for 2 waves/SIMD occupancy.

#define RPB 128        // rows per block
#define THREADS 256    // 4 waves: (rowGroup x oHalf)
#define NFEAT 64
#define NOUT 64
#define OH 32          // outputs per thread
#define PAD 65         // LDS row stride: bank (r+i)%32 -> max 2-way (free)

__global__ __launch_bounds__(THREADS) void kan_bspline_kernel(
    const float* __restrict__ x,
    const float* __restrict__ cp,
    float* __restrict__ out)
{
  __shared__ float xs[RPB * PAD];
  const int tid = threadIdx.x;
  const int r   = tid & (RPB - 1);     // row within block
  const int oh  = tid >> 7;            // 0 or 1: which 32-output half
  const long rowBase = (long)blockIdx.x * RPB;

  // ---- stage x tile (RPB x 64) into LDS, coalesced global reads ----
  #pragma unroll
  for (int k = 0; k < (RPB * NFEAT) / THREADS; ++k) {
    int flat = k * THREADS + tid;       // 0 .. RPB*64-1
    int rr = flat >> 6, f = flat & 63;
    xs[rr * PAD + f] = x[rowBase * 64 + flat];
  }
  __syncthreads();

  float acc[OH];
  #pragma unroll
  for (int o = 0; o < OH; ++o) acc[o] = 0.0f;

  for (int i = 0; i < NFEAT; ++i) {
    float xi = xs[r * PAD + i];
    xi = fminf(fmaxf(xi, 0.0f), 1.0f);

    // interval index: knots[j] <= x < knots[j+1], j = jj+3, jj in [0,8]
    float t9 = xi * 9.0f;
    int jj = (int)t9;
    // reference convention: x==1 lands in degenerate last interval -> basis all zero
    float validf = (jj <= 8) ? 1.0f : 0.0f;
    jj = (jj > 8) ? 8 : jj;
    float fj = (float)jj;
    const float inv9 = 1.0f / 9.0f;
    // knot values: knots[m] = clamp((m-3)/9, 0, 1)
    float km2 = fmaxf(fj - 2.0f, 0.0f) * inv9;   // knots[j-2]
    float km1 = fmaxf(fj - 1.0f, 0.0f) * inv9;   // knots[j-1]
    float k0  = fj * inv9;                        // knots[j]
    float kp1 = fminf(fj + 1.0f, 9.0f) * inv9;    // knots[j+1]
    float kp2 = fminf(fj + 2.0f, 9.0f) * inv9;    // knots[j+2]
    float kp3 = fminf(fj + 3.0f, 9.0f) * inv9;    // knots[j+3]

    // ---- de Boor, degree 3; all denominators >= 1/9 for j in [3,11] ----
    float t  = __builtin_amdgcn_rcpf(kp1 - k0);
    float N0 = (kp1 - xi) * t;
    float N1 = (xi - k0) * t;
    float t0 = N0 * __builtin_amdgcn_rcpf(kp1 - km1);
    float A0 = (kp1 - xi) * t0;
    float s1 = (xi - km1) * t0;
    float t1 = N1 * __builtin_amdgcn_rcpf(kp2 - k0);
    float A1 = s1 + (kp2 - xi) * t1;
    float A2 = (xi - k0) * t1;
    float u0 = A0 * __builtin_amdgcn_rcpf(kp1 - km2);
    float B0 = (kp1 - xi) * u0;
    float s2 = (xi - km2) * u0;
    float u1 = A1 * __builtin_amdgcn_rcpf(kp2 - km1);
    float B1 = s2 + (kp2 - xi) * u1;
    float s3 = (xi - km1) * u1;
    float u2 = A2 * __builtin_amdgcn_rcpf(kp3 - k0);
    float B2 = s3 + (kp3 - xi) * u2;
    float B3 = (xi - k0) * u2;
    B0 *= validf; B1 *= validf; B2 *= validf; B3 *= validf;

    // ---- expand 4-wide support to dense 12 (static indices only) ----
    float b[12];
    #pragma unroll
    for (int c = 0; c < 12; ++c) {
      float v = 0.0f;
      v = (c - jj == 0) ? B0 : v;
      v = (c - jj == 1) ? B1 : v;
      v = (c - jj == 2) ? B2 : v;
      v = (c - jj == 3) ? B3 : v;
      b[c] = v;
    }

    // ---- dense FMA over (c, o-half); cp address is wave-uniform ----
    const float* __restrict__ cpi = cp + i * (12 * 64) + oh * OH;
    #pragma unroll
    for (int c = 0; c < 12; ++c) {
      float bv = b[c];
      const float4* __restrict__ cp4 = (const float4*)(cpi + c * 64);
      #pragma unroll
      for (int o4 = 0; o4 < OH / 4; ++o4) {
        float4 v = cp4[o4];
        acc[o4 * 4 + 0] = fmaf(bv, v.x, acc[o4 * 4 + 0]);
        acc[o4 * 4 + 1] = fmaf(bv, v.y, acc[o4 * 4 + 1]);
        acc[o4 * 4 + 2] = fmaf(bv, v.z, acc[o4 * 4 + 2]);
        acc[o4 * 4 + 3] = fmaf(bv, v.w, acc[o4 * 4 + 3]);
      }
    }
  }

  // rows are read by BOTH oh-waves -> must finish compute before reuse
  __syncthreads();

  // ---- transpose through LDS for coalesced output stores ----
  #pragma unroll
  for (int o = 0; o < OH; ++o) xs[r * PAD + oh * OH + o] = acc[o];
  __syncthreads();
  #pragma unroll
  for (int k = 0; k < (RPB * NOUT) / THREADS; ++k) {
    int flat = k * THREADS + tid;
    int rr = flat >> 6, f = flat & 63;
    out[rowBase * 64 + flat] = xs[rr * PAD + f];
  }
}

extern "C" void kernel_launch(void* const* d_in, const int* in_sizes, int n_in,
                              void* d_out, int out_size, void* d_ws, size_t ws_size,
                              hipStream_t stream) {
  const float* x  = (const float*)d_in[0];
  const float* cp = (const float*)d_in[1];
  float* out = (float*)d_out;
  const int rows = in_sizes[0] / NFEAT;     // 65536
  const int blocks = rows / RPB;            // 512
  hipLaunchKernelGGL(kan_bspline_kernel, dim3(blocks), dim3(THREADS), 0, stream,
                     x, cp, out);
}

// Round 3
// 88.485 us; speedup vs baseline: 4.5581x; 4.5581x over previous
//
#include <hip/hip_runtime.h>

// KAN B-spline layer via MFMA: out[b,o] = sum_k basis[b,k] * W[k,o]
//   basis: (65536 x 768) bf16 built on the fly (K = 64 feats * 12 coeffs)
//   W[k=i*12+c, o] = cp[i,c,o] in bf16, pre-packed into MFMA B-fragments (d_ws)
// x: (65536,64) f32, cp: (64,12,64) f32, out: (65536,64) f32

typedef short short8 __attribute__((ext_vector_type(8)));
typedef float f32x4 __attribute__((ext_vector_type(4)));

#define NFEAT 64
#define KTOT  768
#define NSTEP 24        // K-steps of 32
#define CHUNK 32        // rows per LDS chunk
#define CHUNKS 4
#define RPB   (CHUNK*CHUNKS)   // 128 rows per block
#define THREADS 256
#define LPAD  776       // LDS row stride (bf16 elems): 768+8 -> bank stagger

static __device__ __forceinline__ unsigned bf16rne(float f) {
  unsigned u = __float_as_uint(f);
  return (u + 0x7FFFu + ((u >> 16) & 1u)) >> 16;   // RNE, low 16 bits valid
}

// ---- prep: pack W into per-wave MFMA B-fragments, bf16 ----
// frag element e (0..7) of lane l, step s maps to k = s*32 + (e<4 ? 4g+e : 16+4g+(e-4)),
// g = l>>4. The SAME map is used for the A-side LDS reads in the main kernel, so the
// result is invariant to the hardware's true intra-step k order (common bijection).
__global__ __launch_bounds__(256) void prep_wfrag(const float* __restrict__ cp,
                                                  unsigned* __restrict__ wfrag) {
  int id = blockIdx.x * 256 + threadIdx.x;   // 0 .. 24575 (dwords)
  int d  = id & 3;            // dword within frag (elements 2d, 2d+1)
  int l  = (id >> 2) & 63;    // lane
  int id2 = id >> 8;          // 0..95 = nt*24 + s
  int nt = id2 / NSTEP;
  int s  = id2 - nt * NSTEP;
  int g  = l >> 4;
  int o  = nt * 16 + (l & 15);
  int e0 = 2 * d;
  int k0 = s * 32 + ((e0 < 4) ? (4 * g + e0) : (16 + 4 * g + (e0 - 4)));
  int k1 = k0 + 1;            // e0 even -> e0+1 in same 4-chunk
  unsigned lo = bf16rne(cp[k0 * 64 + o]);
  unsigned hi = bf16rne(cp[k1 * 64 + o]);
  wfrag[id] = lo | (hi << 16);
}

__global__ __launch_bounds__(THREADS) void kan_mfma(const float* __restrict__ x,
                                                    const unsigned* __restrict__ wfrag,
                                                    float* __restrict__ out) {
  __shared__ short bs[CHUNK * LPAD];
  const int tid  = threadIdx.x;
  const int lane = tid & 63;
  const int w    = tid >> 6;            // wave id = n-tile (16 output cols)
  const long rowBase = (long)blockIdx.x * RPB;

  // ---- B fragments for this wave's columns: all K in registers (96 VGPRs) ----
  short8 bfr[NSTEP];
  {
    const short8* wp = (const short8*)wfrag + (w * NSTEP * 64 + lane);
    #pragma unroll
    for (int s = 0; s < NSTEP; ++s) bfr[s] = wp[s * 64];
  }

  const int r  = tid & (CHUNK - 1);     // row within chunk (basis phase)
  const int fg = tid >> 5;              // feature group 0..7 (8 feats each)

  for (int c = 0; c < CHUNKS; ++c) {
    // ================= basis build phase =================
    const float* xrow = x + (rowBase + c * CHUNK + r) * 64 + fg * 8;
    float4 xv0 = ((const float4*)xrow)[0];
    float4 xv1 = ((const float4*)xrow)[1];
    float xs8[8] = {xv0.x, xv0.y, xv0.z, xv0.w, xv1.x, xv1.y, xv1.z, xv1.w};

    #pragma unroll
    for (int e = 0; e < 8; ++e) {
      float xi = fminf(fmaxf(xs8[e], 0.0f), 1.0f);
      float t9 = xi * 9.0f;
      int jj = (int)t9;
      float validf = (jj <= 8) ? 1.0f : 0.0f;   // x==1 -> zero row (ref semantics)
      jj = (jj > 8) ? 8 : jj;
      float fj = (float)jj;
      float u  = t9 - fj;                        // position in interval, [0,1)
      float omu = 1.0f - u;
      // interval-clamped offsets (knot diffs are m/9; 1/9 factors cancel)
      float c1  = fminf(fj, 1.0f);
      float c2  = fminf(fj, 2.0f);
      float rdj = 9.0f - fj;
      float d2p = fminf(rdj, 2.0f);
      float d3p = fminf(rdj, 3.0f);
      // exact inverses (1/m, m in {1,2,3}) via selects
      float invA = (jj == 0) ? 1.0f : 0.5f;                      // kp1-km1
      float invB = (jj == 8) ? 1.0f : 0.5f;                      // kp2-k0
      float invC = (jj == 0) ? 1.0f : ((jj == 1) ? 0.5f : (1.0f/3.0f));   // kp1-km2
      float invD = (jj == 0 || jj == 8) ? 0.5f : (1.0f/3.0f);    // kp2-km1
      float invE = (jj >= 7) ? ((jj == 8) ? 1.0f : 0.5f) : (1.0f/3.0f);   // kp3-k0
      // de Boor (u-space), degree 3
      float xkm1 = u + c1, xkm2 = u + c2;
      float k2x = d2p - u, k3x = d3p - u;
      float t0 = omu * invA;
      float A0 = omu * t0;
      float s1 = xkm1 * t0;
      float t1 = u * invB;
      float A1 = fmaf(k2x, t1, s1);
      float A2 = u * t1;
      float u0 = A0 * invC;
      float B0 = omu * u0;
      float s2 = xkm2 * u0;
      float u1 = A1 * invD;
      float B1 = fmaf(k2x, u1, s2);
      float s3 = xkm1 * u1;
      float u2 = A2 * invE;
      float B2 = fmaf(k3x, u2, s3);
      float B3 = u * u2;
      B0 *= validf; B1 *= validf; B2 *= validf; B3 *= validf;

      // pack sparse support (cols jj..jj+3) into dense 12 bf16 = 6 dwords
      unsigned b0 = bf16rne(B0), b1 = bf16rne(B1), b2 = bf16rne(B2), b3 = bf16rne(B3);
      unsigned p01 = b0 | (b1 << 16);
      unsigned p23 = b2 | (b3 << 16);
      unsigned O0 = p01 << 16;
      unsigned O1 = (p01 >> 16) | (p23 << 16);
      unsigned O2 = p23 >> 16;
      int e2 = jj >> 1;
      bool odd = (jj & 1) != 0;
      unsigned wd[6];
      #pragma unroll
      for (int q = 0; q < 6; ++q) {
        unsigned ve = (q == e2) ? p01 : ((q == e2 + 1) ? p23 : 0u);
        unsigned vo = (q == e2) ? O0 : ((q == e2 + 1) ? O1 : ((q == e2 + 2) ? O2 : 0u));
        wd[q] = odd ? vo : ve;
      }
      uint2* dst = (uint2*)(bs + (r * LPAD + (fg * 8 + e) * 12));
      dst[0] = make_uint2(wd[0], wd[1]);
      dst[1] = make_uint2(wd[2], wd[3]);
      dst[2] = make_uint2(wd[4], wd[5]);
    }

    __syncthreads();

    // ================= MFMA phase =================
    #pragma unroll
    for (int rt = 0; rt < 2; ++rt) {
      f32x4 acc = {0.0f, 0.0f, 0.0f, 0.0f};
      const short* ap = bs + (rt * 16 + (lane & 15)) * LPAD + (lane >> 4) * 4;
      #pragma unroll
      for (int s = 0; s < NSTEP; ++s) {
        union { struct { uint2 a, b; } p; short8 v; } fa;
        fa.p.a = *(const uint2*)(ap + s * 32);        // k = 32s + 4g + 0..3
        fa.p.b = *(const uint2*)(ap + s * 32 + 16);   // k = 32s + 16 + 4g + 0..3
        acc = __builtin_amdgcn_mfma_f32_16x16x32_bf16(fa.v, bfr[s], acc, 0, 0, 0);
      }
      const long orow = rowBase + c * CHUNK + rt * 16 + (lane >> 4) * 4;
      const int  ocol = w * 16 + (lane & 15);
      #pragma unroll
      for (int j = 0; j < 4; ++j)
        out[(orow + j) * 64 + ocol] = acc[j];
    }

    __syncthreads();   // protect LDS before next chunk's basis writes
  }
}

extern "C" void kernel_launch(void* const* d_in, const int* in_sizes, int n_in,
                              void* d_out, int out_size, void* d_ws, size_t ws_size,
                              hipStream_t stream) {
  const float* x  = (const float*)d_in[0];
  const float* cp = (const float*)d_in[1];
  float* out = (float*)d_out;
  unsigned* wfrag = (unsigned*)d_ws;   // 24576 dwords = 96 KB

  hipLaunchKernelGGL(prep_wfrag, dim3(96), dim3(256), 0, stream, cp, wfrag);
  const int rows = in_sizes[0] / NFEAT;          // 65536
  hipLaunchKernelGGL(kan_mfma, dim3(rows / RPB), dim3(THREADS), 0, stream,
                     x, wfrag, out);
}